// Round 3
// baseline (68.429 us; speedup 1.0000x reference)
//
#include <hip/hip_runtime.h>

// KnnConvUnit: B=4, N=8192, K=16, C=64, HID=OUT=128.
// out[b,n,:] = (max_k relu(relu(x@W1+b1)@W2+b2)) @ W3 + b3
//   x=[f,knn,knn-f] -> h1 = relu(knn@Bm + fa),  fa = f@Aw + b1   (fA split out)
//   Bm = W1[64:128]+W1[128:192], Aw = W1[0:64]-W1[128:192]
// v_mfma_f32_16x16x32_f16 everywhere, shared k-permutation
//   kappa(g,j) = 16*(j>>2) + 4*g + (j&3)
// Block = 512 thr (8 waves) x ITERS=4 groups of 16 points = 64 pts/block.
// Grid = 512 = 2 blocks/CU exactly. Weights staged once per block.

#define BB 4
#define NN 8192
#define KK 16
#define CC 64
#define HH 128
#define ITERS 4

typedef _Float16 f16;
typedef _Float16 f16x8 __attribute__((ext_vector_type(8)));
typedef float f32x4 __attribute__((ext_vector_type(4)));

#define MFMA16(a, b, c) __builtin_amdgcn_mfma_f32_16x16x32_f16(a, b, c, 0, 0, 0)

// ---------------- prep: pack weights, fragment-linear f16, kappa k-order ----
// fid 0..15 : Bm A-frags (ht*2+kt, kt<2)      | fid 16..47: W2 (16+h2t*4+kt)
// fid 48..63: Aw A-frags (48+ht*2+kt, kt<2)   | fid 64..95: W3 (64+ot*4+kt)
__global__ void prep_pack(const float* __restrict__ W1, const float* __restrict__ W2,
                          const float* __restrict__ W3, f16* __restrict__ ws) {
  int fid = blockIdx.x;
  int l = threadIdx.x;
  int g = l >> 4, r = l & 15;
  f16x8 v;
#pragma unroll
  for (int j = 0; j < 8; ++j) {
    int kl = 16 * (j >> 2) + 4 * g + (j & 3);   // kappa(g,j)
    float x;
    if (fid < 16) {
      int ht = fid >> 1, kt = fid & 1, h = ht * 16 + r, k = kt * 32 + kl;
      x = W1[(64 + k) * HH + h] + W1[(128 + k) * HH + h];      // Bm
    } else if (fid < 48) {
      int t = fid - 16, h2t = t >> 2, kt = t & 3;
      x = W2[(kt * 32 + kl) * HH + h2t * 16 + r];
    } else if (fid < 64) {
      int t = fid - 48, ht = t >> 1, kt = t & 1, h = ht * 16 + r, k = kt * 32 + kl;
      x = W1[k * HH + h] - W1[(128 + k) * HH + h];             // Aw
    } else {
      int t = fid - 64, ot = t >> 2, kt = t & 3;
      x = W3[(kt * 32 + kl) * HH + ot * 16 + r];
    }
    v[j] = (f16)x;
  }
  *(f16x8*)(ws + (size_t)fid * 512 + l * 8) = v;
}

// ---------------- main ----------------
// LDS: wbuf 48 frags (48KB) | fabuf [2][16][132] f32 (16896B)
//      pooled [2][4 frags] (8192B)  -> total 74240 B -> 2 blocks/CU
__global__ __launch_bounds__(512, 4) void knn_main(
    const float* __restrict__ f, const int* __restrict__ knn,
    const float* __restrict__ b1, const float* __restrict__ b2,
    const float* __restrict__ b3, const f16* __restrict__ ws,
    float* __restrict__ out) {
  extern __shared__ char smem[];
  f16* wbuf = (f16*)smem;                       // 48*512 f16
  float* fabuf = (float*)(wbuf + 48 * 512);     // [2][16][132] f32
  f16* pooled = (f16*)(fabuf + 2 * 16 * 132);   // [2][2048] f16

  const int tid = threadIdx.x;
  const int wave = tid >> 6, lane = tid & 63;
  const int g = lane >> 4, r = lane & 15;

  // XCD-aware swizzle: 512 blocks, 8 XCDs -> 64 contiguous groups per XCD
  const int wg = (blockIdx.x & 7) * 64 + (blockIdx.x >> 3);
  const int b = wg >> 7;                // 128 blocks per batch
  const int nbase = (wg & 127) * 64;
  const float* fb = f + (size_t)b * NN * CC;
  const int p0 = wave * 2;

  // --- stage 48 weight frags (Bm + W2) into LDS, reg-staged, linear ---
  f16x8 st[6];
#pragma unroll
  for (int i = 0; i < 6; ++i)
    st[i] = *(const f16x8*)(ws + (size_t)(i * 512 + tid) * 8);
#pragma unroll
  for (int i = 0; i < 6; ++i)
    *(f16x8*)(wbuf + (size_t)(i * 512 + tid) * 8) = st[i];

  // --- nidx for iter 0 ---
  int nidx[2];
#pragma unroll
  for (int pp = 0; pp < 2; ++pp)
    nidx[pp] = knn[((size_t)b * NN + nbase + p0 + pp) * KK + r];

  for (int it = 0; it < ITERS; ++it) {
    const int n0 = nbase + it * 16;
    const int buf = it & 1;

    // A) issue neighbor gathers first (longest latency)
    f32x4 rawA[2][2][2];
#pragma unroll
    for (int pp = 0; pp < 2; ++pp) {
      const float* frow = fb + (size_t)nidx[pp] * CC;
#pragma unroll
      for (int kt = 0; kt < 2; ++kt) {
        rawA[pp][kt][0] = *(const f32x4*)(frow + kt * 32 + 4 * g);
        rawA[pp][kt][1] = *(const f32x4*)(frow + kt * 32 + 4 * g + 16);
      }
    }
    // B) own rows for fA (B-frag col r = point n0+r)
    const float* fo = fb + (size_t)(n0 + r) * CC;
    f32x4 rawO[2][2];
#pragma unroll
    for (int kt = 0; kt < 2; ++kt) {
      rawO[kt][0] = *(const f32x4*)(fo + kt * 32 + 4 * g);
      rawO[kt][1] = *(const f32x4*)(fo + kt * 32 + 4 * g + 16);
    }
    // C) prefetch next iter's knn indices
    const int itn = (it < ITERS - 1) ? it + 1 : it;
    int nidn[2];
#pragma unroll
    for (int pp = 0; pp < 2; ++pp)
      nidn[pp] = knn[((size_t)b * NN + nbase + itn * 16 + p0 + pp) * KK + r];

    // D) fA: fa[h=wave-tile][16 pts] = f@Aw + b1
    {
      f32x4 acc = {0.f, 0.f, 0.f, 0.f};
#pragma unroll
      for (int kt = 0; kt < 2; ++kt) {
        f16x8 aw = *(const f16x8*)(ws + (size_t)(48 + wave * 2 + kt) * 512 + lane * 8);
        f16x8 bfa;
#pragma unroll
        for (int jl = 0; jl < 4; ++jl) {
          bfa[jl] = (f16)rawO[kt][0][jl];
          bfa[4 + jl] = (f16)rawO[kt][1][jl];
        }
        acc = MFMA16(aw, bfa, acc);
      }
      f32x4 b1v = *(const f32x4*)(b1 + wave * 16 + g * 4);
      f32x4 fa;
#pragma unroll
      for (int i = 0; i < 4; ++i) fa[i] = acc[i] + b1v[i];
      *(f32x4*)(fabuf + buf * 2112 + r * 132 + wave * 16 + g * 4) = fa;
    }

    __syncthreads();   // (1) fabuf + wbuf ready

    // F) convert gathered rows to B-frags
    f16x8 bf[2][2];
#pragma unroll
    for (int pp = 0; pp < 2; ++pp)
#pragma unroll
      for (int kt = 0; kt < 2; ++kt)
#pragma unroll
        for (int jl = 0; jl < 4; ++jl) {
          bf[pp][kt][jl] = (f16)rawA[pp][kt][0][jl];
          bf[pp][kt][4 + jl] = (f16)rawA[pp][kt][1][jl];
        }

    // G) L1: C[h][nbr] = Bm^T x knn (K=64), + fa, relu -> h1 regs
    f16x8 h1f[2][4];
#pragma unroll
    for (int ht = 0; ht < 8; ++ht) {
      f16x8 w0 = *(const f16x8*)(wbuf + (size_t)(ht * 2 + 0) * 512 + lane * 8);
      f16x8 w1 = *(const f16x8*)(wbuf + (size_t)(ht * 2 + 1) * 512 + lane * 8);
      f32x4 a0 = {0.f, 0.f, 0.f, 0.f}, a1 = {0.f, 0.f, 0.f, 0.f};
      a0 = MFMA16(w0, bf[0][0], a0);
      a0 = MFMA16(w1, bf[0][1], a0);
      a1 = MFMA16(w0, bf[1][0], a1);
      a1 = MFMA16(w1, bf[1][1], a1);
      f32x4 fa0 = *(const f32x4*)(fabuf + buf * 2112 + (p0 + 0) * 132 + ht * 16 + g * 4);
      f32x4 fa1 = *(const f32x4*)(fabuf + buf * 2112 + (p0 + 1) * 132 + ht * 16 + g * 4);
#pragma unroll
      for (int i = 0; i < 4; ++i) {
        float x0 = a0[i] + fa0[i];
        float x1 = a1[i] + fa1[i];
        h1f[0][ht >> 1][(ht & 1) * 4 + i] = (f16)(x0 > 0.f ? x0 : 0.f);
        h1f[1][ht >> 1][(ht & 1) * 4 + i] = (f16)(x1 > 0.f ? x1 : 0.f);
      }
    }

    // H) L2: C[nbr][h2] = h1 x W2; pool = 3 v_max + 2 shfl
#pragma unroll
    for (int h2t = 0; h2t < 8; ++h2t) {
      f32x4 c0 = {0.f, 0.f, 0.f, 0.f}, c1 = {0.f, 0.f, 0.f, 0.f};
#pragma unroll
      for (int kt = 0; kt < 4; ++kt) {
        f16x8 w2f = *(const f16x8*)(wbuf + (size_t)(16 + h2t * 4 + kt) * 512 + lane * 8);
        c0 = MFMA16(h1f[0][kt], w2f, c0);
        c1 = MFMA16(h1f[1][kt], w2f, c1);
      }
      float b2v = b2[h2t * 16 + r];
#pragma unroll
      for (int pp = 0; pp < 2; ++pp) {
        f32x4 cc = pp ? c1 : c0;
        float m = fmaxf(fmaxf(cc[0], cc[1]), fmaxf(cc[2], cc[3]));
        m = fmaxf(m, __shfl_xor(m, 16, 64));
        m = fmaxf(m, __shfl_xor(m, 32, 64));
        float x = m + b2v;
        f16 pv = (f16)(x > 0.f ? x : 0.f);
        if (g == 0) {
          pooled[buf * 2048 + (h2t >> 1) * 512 + ((r >> 2) * 16 + p0 + pp) * 8 +
                 (h2t & 1) * 4 + (r & 3)] = pv;
        }
      }
    }

    __syncthreads();   // (2) pooled ready

    // J) L3: C[od][pt] = W3^T x pooled
    {
      f32x4 a3 = {0.f, 0.f, 0.f, 0.f};
#pragma unroll
      for (int kt = 0; kt < 4; ++kt) {
        f16x8 w3f = *(const f16x8*)(ws + (size_t)(64 + wave * 4 + kt) * 512 + lane * 8);
        f16x8 pf = *(const f16x8*)(pooled + buf * 2048 + kt * 512 + lane * 8);
        a3 = MFMA16(w3f, pf, a3);
      }
      f32x4 b3v = *(const f32x4*)(b3 + wave * 16 + g * 4);
      f32x4 o;
#pragma unroll
      for (int i = 0; i < 4; ++i) o[i] = a3[i] + b3v[i];
      *(f32x4*)(out + ((size_t)b * NN + n0 + r) * HH + wave * 16 + g * 4) = o;
    }

    nidx[0] = nidn[0];
    nidx[1] = nidn[1];
  }
}

extern "C" void kernel_launch(void* const* d_in, const int* in_sizes, int n_in,
                              void* d_out, int out_size, void* d_ws, size_t ws_size,
                              hipStream_t stream) {
  const float* f = (const float*)d_in[0];
  const int* knn = (const int*)d_in[1];
  const float* W1 = (const float*)d_in[2];
  const float* b1 = (const float*)d_in[3];
  const float* W2 = (const float*)d_in[4];
  const float* b2 = (const float*)d_in[5];
  const float* W3 = (const float*)d_in[6];
  const float* b3 = (const float*)d_in[7];
  float* outp = (float*)d_out;
  f16* wsp = (f16*)d_ws;   // 96 frags * 1KB = 96KB scratch

  (void)hipFuncSetAttribute((const void*)knn_main,
                            hipFuncAttributeMaxDynamicSharedMemorySize, 74240);

  prep_pack<<<96, 64, 0, stream>>>(W1, W2, W3, wsp);
  knn_main<<<(BB * NN) / (16 * ITERS), 512, 74240, stream>>>(f, knn, b1, b2, b3, wsp, outp);
}